// Round 7
// baseline (273.272 us; speedup 1.0000x reference)
//
#include <hip/hip_runtime.h>

// SSIM loss v8 — wave-autonomous strips, ZERO barriers:
//   Evidence base (v3-v7): VALUBusy pinned 58-67% across occupancy 26/33/67%,
//   across prefetch placement (T14), and across a 7% work cut (v7: FETCH -7%
//   but time flat, VALUBusy -6pts). => latency-bound via the barrier-interval
//   convoy: 4 waves/block lockstep at __syncthreads 37-69x/block; convoyed
//   waves stall together so occupancy/work changes never moved time.
//   v8 removes the coupling entirely:
//   - each WAVE owns a 64-col x 64-row output strip with a private LDS buffer
//     (74 staged cols = 64 + 5 halo each side; lanes 0-9 stage the 10 extra).
//   - CDNA waves are strictly lockstep -> ds_write + s_waitcnt lgkmcnt(0)
//     makes own-wave writes visible for ds_read: NO s_barrier anywhere.
//     (asm volatile with "memory" clobber = compiler fence so the reads
//     cannot be hoisted above the wait; same-wave DS ops drain at lgkmcnt=0.)
//   - all waves fully independent -> no convoy; each wave's LDS/global
//     latency hides under other waves' compute.
//   - same row-pair packed-v2f conv math, 6-entry ring, T14 prefetch order
//     (issue i+1's global loads right after the wait, before compute(i)).
//   - block reduce gone: one double atomicAdd per wave (6144 total).
//   Grid: 8 col-strips x 8 row-bands x 96 planes = 6144 strips = 1536 blocks
//   of 4 independent waves. LDS 2 slots x 80 float4 x 4 waves = 10.2 KB/block.
//   Launch bounds: plain (256). (256,6) spilled catastrophically in v4
//   (VGPR 64->40, WRITE_SIZE 48KB->200MB); spill tripwire: WRITE_SIZE must
//   stay KB-scale.
// B=32, C=3, H=W=512 fp32; zero padding (pad=5) matches lax conv semantics.

typedef float v2f __attribute__((ext_vector_type(2)));
typedef float v4f __attribute__((ext_vector_type(4)));

constexpr int IMG    = 512;
constexpr int TPB    = 256;            // 4 independent waves per block
constexpr int WPB    = 4;              // waves per block
constexpr int SW     = 64;             // output cols per wave strip
constexpr int SH     = 64;             // output rows per wave strip
constexpr int NPAIR  = (SH + 10) / 2;  // 37 input row-pairs (74 rows)
constexpr int LE     = 80;             // float4 entries per slot (74 used)
constexpr int NSX    = IMG / SW;       // 8
constexpr int NSY    = IMG / SH;       // 8
constexpr int PLANES = 32 * 3;         // 96
constexpr int NSTRIP = NSX * NSY * PLANES;   // 6144
constexpr double N_PIX = 25165824.0;   // 32*3*512*512

__global__ __launch_bounds__(TPB) void ssim_map_kernel(
    const float* __restrict__ img1, const float* __restrict__ img2,
    double* __restrict__ partial)
{
    constexpr float GW[11] = {
        0.0010283801f, 0.0075987583f, 0.0360007721f, 0.1093607008f,
        0.2130055439f, 0.2660117257f, 0.2130055439f, 0.1093607008f,
        0.0360007721f, 0.0075987583f, 0.0010283801f };
    // GWp[k+1] = GW[k], zero-extended both sides (for edge taps of row pairs)
    constexpr float GWp[13] = {
        0.0f,
        0.0010283801f, 0.0075987583f, 0.0360007721f, 0.1093607008f,
        0.2130055439f, 0.2660117257f, 0.2130055439f, 0.1093607008f,
        0.0360007721f, 0.0075987583f, 0.0010283801f,
        0.0f };

    __shared__ v4f sbuf[WPB][2][LE];   // per-wave private double buffer

    const int tid  = threadIdx.x;
    const int wid  = tid >> 6;
    const int lane = tid & 63;

    // strip decode: s = xs + 8*ys + 64*plane
    const int s     = blockIdx.x * WPB + wid;
    const int xs    = s & (NSX - 1);
    const int ys    = (s >> 3) & (NSY - 1);
    const int plane = s >> 6;

    const int x0 = xs * SW;
    const int y0 = ys * SH;

    const float* p1 = img1 + (size_t)plane * IMG * IMG;
    const float* p2 = img2 + (size_t)plane * IMG * IMG;

    // staging columns: entry L=lane -> col x0+lane-5 ; halo entry L=64+lane
    // (lane<10) -> col x0+59+lane. Out-of-range columns/rows stage 0.0f.
    const int  c    = x0 + lane - 5;
    const bool cok  = (unsigned)c < (unsigned)IMG;
    const int  c2   = x0 + 59 + lane;                  // lanes 0..9 only
    const bool c2ok = (unsigned)c2 < (unsigned)IMG;

    // 6-entry row-pair rings for the 5 horizontally-convolved quantities
    v2f rg1[6], rg2[6], rg11[6], rg22[6], rg12[6];

    v2f accv = {0.0f, 0.0f};

    // prefetch registers for the next row pair (4 main + 4 halo)
    float pa1, pb1, pa2, pb2, qa1, qb1, qa2, qb2;
    auto prefetch = [&](int i) {
        const int  rA  = y0 - 5 + 2 * i;
        const int  rB  = rA + 1;
        const bool aok = (unsigned)rA < (unsigned)IMG;
        const bool bok = (unsigned)rB < (unsigned)IMG;
        const size_t oA = (size_t)rA * IMG;
        const size_t oB = (size_t)rB * IMG;
        pa1 = (aok && cok) ? p1[oA + c] : 0.0f;
        pb1 = (bok && cok) ? p1[oB + c] : 0.0f;
        pa2 = (aok && cok) ? p2[oA + c] : 0.0f;
        pb2 = (bok && cok) ? p2[oB + c] : 0.0f;
        if (lane < 10) {
            qa1 = (aok && c2ok) ? p1[oA + c2] : 0.0f;
            qb1 = (bok && c2ok) ? p1[oB + c2] : 0.0f;
            qa2 = (aok && c2ok) ? p2[oA + c2] : 0.0f;
            qb2 = (bok && c2ok) ? p2[oB + c2] : 0.0f;
        }
    };

    prefetch(0);

    for (int ib = 0; ib < NPAIR; ib += 6) {
#pragma unroll
        for (int j = 0; j < 6; ++j) {
            const int i = ib + j;
            if (i < NPAIR) {
                const int sl = j & 1;   // ib is even -> slot alternates with i
                // stage prefetched row pair into this wave's slot. Consuming
                // pf regs waits vmcnt for loads issued LAST iteration —
                // latency covered by compute(i-1).
                sbuf[wid][sl][lane] = v4f{pa1, pb1, pa2, pb2};
                if (lane < 10) sbuf[wid][sl][64 + lane] = v4f{qa1, qb1, qa2, qb2};
                // wave-synchronous visibility: all 64 lanes' ds_writes have
                // committed once lgkmcnt==0 (lockstep wave, private buffer).
                // "memory" clobber fences the compiler from hoisting reads.
                asm volatile("s_waitcnt lgkmcnt(0)" ::: "memory");

                // issue NEXT pair's global loads now: they fly under the
                // horizontal+vertical conv below (T14 issue-early)
                if (i + 1 < NPAIR) prefetch(i + 1);

                // horizontal 11-tap conv for this thread's column, both rows
                v2f a1 = {0,0}, a2 = {0,0}, a11 = {0,0}, a22 = {0,0}, a12 = {0,0};
                const v4f* sp = &sbuf[wid][sl][lane];
#pragma unroll
                for (int k = 0; k < 11; ++k) {
                    const v4f sv = sp[k];
                    const v2f x1 = __builtin_shufflevector(sv, sv, 0, 1);
                    const v2f x2 = __builtin_shufflevector(sv, sv, 2, 3);
                    const float g = GW[k];
                    const v2f t1 = g * x1;
                    const v2f t2 = g * x2;
                    a1 += t1;
                    a2 += t2;
                    a11 = __builtin_elementwise_fma(t1, x1, a11);
                    a22 = __builtin_elementwise_fma(t2, x2, a22);
                    a12 = __builtin_elementwise_fma(t1, x2, a12);
                }
                rg1[j] = a1;  rg2[j] = a2;
                rg11[j] = a11; rg22[j] = a22; rg12[j] = a12;
            }

            if (i >= 5 && i < NPAIR) {
                // vertical conv for output rows (y0+2q, y0+2q+1), q = i-5.
                // ring entry m (input pair q+m) sits at slot (j+1+m)%6.
                // out.x taps: {g[2m], g[2m+1]} ; out.y taps: {g[2m-1], g[2m]}
                v2f sx1={0,0}, sy1={0,0}, sx2={0,0}, sy2={0,0};
                v2f sx11={0,0}, sy11={0,0}, sx22={0,0}, sy22={0,0};
                v2f sx12={0,0}, sy12={0,0};
#pragma unroll
                for (int m = 0; m < 6; ++m) {
                    const int sr = (j + 1 + m) % 6;
                    const v2f wx = { GWp[2*m + 1], GWp[2*m + 2] };
                    const v2f wy = { GWp[2*m],     GWp[2*m + 1] };
                    sx1  = __builtin_elementwise_fma(wx, rg1[sr],  sx1);
                    sy1  = __builtin_elementwise_fma(wy, rg1[sr],  sy1);
                    sx2  = __builtin_elementwise_fma(wx, rg2[sr],  sx2);
                    sy2  = __builtin_elementwise_fma(wy, rg2[sr],  sy2);
                    sx11 = __builtin_elementwise_fma(wx, rg11[sr], sx11);
                    sy11 = __builtin_elementwise_fma(wy, rg11[sr], sy11);
                    sx22 = __builtin_elementwise_fma(wx, rg22[sr], sx22);
                    sy22 = __builtin_elementwise_fma(wy, rg22[sr], sy22);
                    sx12 = __builtin_elementwise_fma(wx, rg12[sr], sx12);
                    sy12 = __builtin_elementwise_fma(wy, rg12[sr], sy12);
                }
                // lane-sum each pk-dot -> {row r, row r+1} packed values
                const v2f m1  = { sx1.x + sx1.y,  sy1.x + sy1.y };
                const v2f m2  = { sx2.x + sx2.y,  sy2.x + sy2.y };
                const v2f e11 = { sx11.x + sx11.y, sy11.x + sy11.y };
                const v2f e22 = { sx22.x + sx22.y, sy22.x + sy22.y };
                const v2f e12 = { sx12.x + sx12.y, sy12.x + sy12.y };

                const v2f mu11 = m1 * m1;
                const v2f mu22 = m2 * m2;
                const v2f mu12 = m1 * m2;
                const v2f zero = {0.0f, 0.0f};
                const v2f one  = {1.0f, 1.0f};
                const v2f sg1  = __builtin_elementwise_max(e11 - mu11, zero);
                const v2f sg2  = __builtin_elementwise_max(e22 - mu22, zero);
                const v2f sg12 = e12 - mu12;
                const v2f num = (2.0f * mu12 + 1e-4f) * (2.0f * sg12 + 9e-4f);
                const v2f den = (mu11 + mu22 + 1e-4f) * (sg1 + sg2 + 9e-4f);
                v2f v = { num.x * __builtin_amdgcn_rcpf(den.x),
                          num.y * __builtin_amdgcn_rcpf(den.y) };
                v = __builtin_elementwise_min(__builtin_elementwise_max(v, zero), one);
                accv += v;
            }
        }
    }

    // wave-level reduction, one double atomic per wave (no block sync needed)
    float acc = accv.x + accv.y;
#pragma unroll
    for (int off = 32; off > 0; off >>= 1)
        acc += __shfl_down(acc, off, 64);
    if (lane == 0)
        atomicAdd(partial, (double)acc);
}

__global__ void ssim_finalize_kernel(const double* __restrict__ partial,
                                     float* __restrict__ out)
{
    out[0] = 1.0f - (float)(partial[0] / N_PIX);
}

extern "C" void kernel_launch(void* const* d_in, const int* in_sizes, int n_in,
                              void* d_out, int out_size, void* d_ws, size_t ws_size,
                              hipStream_t stream) {
    const float* img1 = (const float*)d_in[0];
    const float* img2 = (const float*)d_in[1];
    float* out = (float*)d_out;
    double* acc = (double*)d_ws;

    hipMemsetAsync(acc, 0, sizeof(double), stream);  // ws re-poisoned each launch

    dim3 grid(NSTRIP / WPB);                         // 1536 blocks x 4 waves
    ssim_map_kernel<<<grid, TPB, 0, stream>>>(img1, img2, acc);
    ssim_finalize_kernel<<<1, 1, 0, stream>>>(acc, out);
}

// Round 8
// 256.818 us; speedup vs baseline: 1.0641x; 1.0641x over previous
//
#include <hip/hip_runtime.h>

// SSIM loss v9 — TWO row-pairs per barrier interval:
//   Evidence (v3-v8): time pinned ~114us, VALUBusy 58-67% across occupancy
//   26/33/67%, prefetch placement, -7% work (v7: flat), and ZERO barriers
//   (v8: WORSE, 137us — wave-private fence serialized the wave; halo +13%).
//   All variants shared one invariant: ~220 serial intervals per SIMD, each a
//   {ds_write -> sync -> ds_read(~120cy) -> FMA} chain with only ~3-way wave
//   overlap; total intervals/SIMD was constant in every experiment (6x37 vs
//   3x69) and so was time. v9 HALVES the chain count at constant work:
//   - each interval stages TWO row pairs (4 LDS slots), ONE barrier (19/blk),
//     prefetches 2 pairs (16 loads in flight = 2x MLP),
//     then {hconvA; vertA; hconvB; vertB} — ring stays 6 entries because
//     pair p0+1 enters the ring only after vert(p0) consumed pair p0-5.
//   - slot schedule: intervals alternate slots {0,1}/{2,3}; reuse distance 2
//     intervals with a barrier between -> WAR-safe (same logic as v3's
//     triple buffer).
//   - outer loop stays runtime (ib+=12, 6 unrolled intervals) -> same I-cache
//     footprint as v6.
//   - launch bounds (256,3): proven no-spill config ((256,6) spilled: VGPR
//     64->40, WRITE_SIZE 48KB->200MB). Spill tripwire: WRITE_SIZE ~KB-scale.
//   - T14 order kept: prefetch issued after the barrier, consumed next
//     interval's stage (vmcnt hidden under ~2x conv compute).
// B=32, C=3, H=W=512 fp32; zero padding (pad=5) matches lax conv semantics.

typedef float v2f __attribute__((ext_vector_type(2)));
typedef float v4f __attribute__((ext_vector_type(4)));

constexpr int IMG    = 512;
constexpr int TPB    = 256;          // threads/block; 1 col/thread
constexpr int SH     = 64;           // output rows per block
constexpr int NPAIR  = 37;           // input row-pairs streamed (74 rows)
constexpr int LW     = 272;          // LDS float4 entries per slot (8 pad each side)
constexpr int PLANES = 32 * 3;       // 96
constexpr double N_PIX = 25165824.0; // 32*3*512*512

__global__ __launch_bounds__(TPB, 3) void ssim_map_kernel(
    const float* __restrict__ img1, const float* __restrict__ img2,
    double* __restrict__ partial)
{
    constexpr float GW[11] = {
        0.0010283801f, 0.0075987583f, 0.0360007721f, 0.1093607008f,
        0.2130055439f, 0.2660117257f, 0.2130055439f, 0.1093607008f,
        0.0360007721f, 0.0075987583f, 0.0010283801f };
    // GWp[k+1] = GW[k], zero-extended both sides (for edge taps of row pairs)
    constexpr float GWp[13] = {
        0.0f,
        0.0010283801f, 0.0075987583f, 0.0360007721f, 0.1093607008f,
        0.2130055439f, 0.2660117257f, 0.2130055439f, 0.1093607008f,
        0.0360007721f, 0.0075987583f, 0.0010283801f,
        0.0f };

    __shared__ v4f  sbuf[4][LW];     // 4 slots: {0,1}/{2,3} alternate per interval
    __shared__ float wsum[TPB / 64];

    const int tid   = threadIdx.x;
    const int x0    = blockIdx.x * TPB;     // 0 or 256
    const int y0    = blockIdx.y * SH;
    const int plane = blockIdx.z;

    const float* p1 = img1 + (size_t)plane * IMG * IMG;
    const float* p2 = img2 + (size_t)plane * IMG * IMG;

    // staging columns: main entry L=tid -> col x0+tid-8 ; halo entry L=256+tid
    // (tid<16) -> col x0+248+tid. Out-of-range columns/rows stage 0.0f.
    const int  c   = x0 + tid - 8;
    const bool cok = (unsigned)c < (unsigned)IMG;
    const int  c2  = x0 + 248 + tid;
    const bool c2ok = (unsigned)c2 < (unsigned)IMG;   // only used when tid<16

    // 6-entry row-pair rings for the 5 horizontally-convolved quantities
    v2f rg1[6], rg2[6], rg11[6], rg22[6], rg12[6];

    v2f accv = {0.0f, 0.0f};

    // prefetch registers, SET A (even pairs) and SET B (odd pairs)
    float pa1, pb1, pa2, pb2, qa1, qb1, qa2, qb2;
    float ra1, rb1, ra2, rb2, sa1, sb1, sa2, sb2;

    auto prefetchA = [&](int i) {
        const int  rA  = y0 - 5 + 2 * i;
        const int  rB  = rA + 1;
        const bool aok = (unsigned)rA < (unsigned)IMG;
        const bool bok = (unsigned)rB < (unsigned)IMG;
        const size_t oA = (size_t)rA * IMG;
        const size_t oB = (size_t)rB * IMG;
        pa1 = (aok && cok) ? p1[oA + c] : 0.0f;
        pb1 = (bok && cok) ? p1[oB + c] : 0.0f;
        pa2 = (aok && cok) ? p2[oA + c] : 0.0f;
        pb2 = (bok && cok) ? p2[oB + c] : 0.0f;
        if (tid < 16) {
            qa1 = (aok && c2ok) ? p1[oA + c2] : 0.0f;
            qb1 = (bok && c2ok) ? p1[oB + c2] : 0.0f;
            qa2 = (aok && c2ok) ? p2[oA + c2] : 0.0f;
            qb2 = (bok && c2ok) ? p2[oB + c2] : 0.0f;
        }
    };
    auto prefetchB = [&](int i) {
        const int  rA  = y0 - 5 + 2 * i;
        const int  rB  = rA + 1;
        const bool aok = (unsigned)rA < (unsigned)IMG;
        const bool bok = (unsigned)rB < (unsigned)IMG;
        const size_t oA = (size_t)rA * IMG;
        const size_t oB = (size_t)rB * IMG;
        ra1 = (aok && cok) ? p1[oA + c] : 0.0f;
        rb1 = (bok && cok) ? p1[oB + c] : 0.0f;
        ra2 = (aok && cok) ? p2[oA + c] : 0.0f;
        rb2 = (bok && cok) ? p2[oB + c] : 0.0f;
        if (tid < 16) {
            sa1 = (aok && c2ok) ? p1[oA + c2] : 0.0f;
            sb1 = (bok && c2ok) ? p1[oB + c2] : 0.0f;
            sa2 = (aok && c2ok) ? p2[oA + c2] : 0.0f;
            sb2 = (bok && c2ok) ? p2[oB + c2] : 0.0f;
        }
    };

    // horizontal 11-tap conv from LDS slot -> ring entry rs
    auto hconv = [&](int slot, int rs) {
        v2f a1 = {0,0}, a2 = {0,0}, a11 = {0,0}, a22 = {0,0}, a12 = {0,0};
        const v4f* sp = &sbuf[slot][tid + 3];
#pragma unroll
        for (int k = 0; k < 11; ++k) {
            const v4f s  = sp[k];
            const v2f x1 = __builtin_shufflevector(s, s, 0, 1);
            const v2f x2 = __builtin_shufflevector(s, s, 2, 3);
            const float g = GW[k];
            const v2f t1 = g * x1;
            const v2f t2 = g * x2;
            a1 += t1;
            a2 += t2;
            a11 = __builtin_elementwise_fma(t1, x1, a11);
            a22 = __builtin_elementwise_fma(t2, x2, a22);
            a12 = __builtin_elementwise_fma(t1, x2, a12);
        }
        rg1[rs] = a1;  rg2[rs] = a2;
        rg11[rs] = a11; rg22[rs] = a22; rg12[rs] = a12;
    };

    // vertical conv + epilogue for pair with ring residue r (= p % 6).
    // ring entry m (input pair q+m, q=p-5) sits at slot (r+1+m)%6.
    auto vert = [&](int r) {
        v2f sx1={0,0}, sy1={0,0}, sx2={0,0}, sy2={0,0};
        v2f sx11={0,0}, sy11={0,0}, sx22={0,0}, sy22={0,0};
        v2f sx12={0,0}, sy12={0,0};
#pragma unroll
        for (int m = 0; m < 6; ++m) {
            const int s = (r + 1 + m) % 6;
            const v2f wx = { GWp[2*m + 1], GWp[2*m + 2] };
            const v2f wy = { GWp[2*m],     GWp[2*m + 1] };
            sx1  = __builtin_elementwise_fma(wx, rg1[s],  sx1);
            sy1  = __builtin_elementwise_fma(wy, rg1[s],  sy1);
            sx2  = __builtin_elementwise_fma(wx, rg2[s],  sx2);
            sy2  = __builtin_elementwise_fma(wy, rg2[s],  sy2);
            sx11 = __builtin_elementwise_fma(wx, rg11[s], sx11);
            sy11 = __builtin_elementwise_fma(wy, rg11[s], sy11);
            sx22 = __builtin_elementwise_fma(wx, rg22[s], sx22);
            sy22 = __builtin_elementwise_fma(wy, rg22[s], sy22);
            sx12 = __builtin_elementwise_fma(wx, rg12[s], sx12);
            sy12 = __builtin_elementwise_fma(wy, rg12[s], sy12);
        }
        const v2f m1  = { sx1.x + sx1.y,  sy1.x + sy1.y };
        const v2f m2  = { sx2.x + sx2.y,  sy2.x + sy2.y };
        const v2f e11 = { sx11.x + sx11.y, sy11.x + sy11.y };
        const v2f e22 = { sx22.x + sx22.y, sy22.x + sy22.y };
        const v2f e12 = { sx12.x + sx12.y, sy12.x + sy12.y };

        const v2f mu11 = m1 * m1;
        const v2f mu22 = m2 * m2;
        const v2f mu12 = m1 * m2;
        const v2f zero = {0.0f, 0.0f};
        const v2f one  = {1.0f, 1.0f};
        const v2f sg1  = __builtin_elementwise_max(e11 - mu11, zero);
        const v2f sg2  = __builtin_elementwise_max(e22 - mu22, zero);
        const v2f sg12 = e12 - mu12;
        const v2f num = (2.0f * mu12 + 1e-4f) * (2.0f * sg12 + 9e-4f);
        const v2f den = (mu11 + mu22 + 1e-4f) * (sg1 + sg2 + 9e-4f);
        v2f v = { num.x * __builtin_amdgcn_rcpf(den.x),
                  num.y * __builtin_amdgcn_rcpf(den.y) };
        v = __builtin_elementwise_min(__builtin_elementwise_max(v, zero), one);
        accv += v;
    };

    prefetchA(0);
    prefetchB(1);

    // 19 intervals of 2 pairs; ib steps 12 pairs (6 intervals) so ring (%6)
    // and slot (%4) residues are compile-time in the unrolled inner loop.
    for (int ib = 0; ib < NPAIR; ib += 12) {
#pragma unroll
        for (int jj = 0; jj < 6; ++jj) {
            const int p0 = ib + 2 * jj;
            const int p1i = p0 + 1;
            const int s0 = (2 * jj) % 4;
            const int s1 = (2 * jj + 1) % 4;
            const int r0 = (2 * jj) % 6;
            const int r1 = (2 * jj + 1) % 6;

            // stage both prefetched pairs (consumes pf regs -> vmcnt wait
            // covered by last interval's 2x conv compute)
            if (p0 < NPAIR) {
                sbuf[s0][tid] = v4f{pa1, pb1, pa2, pb2};
                if (tid < 16) sbuf[s0][256 + tid] = v4f{qa1, qb1, qa2, qb2};
            }
            if (p1i < NPAIR) {
                sbuf[s1][tid] = v4f{ra1, rb1, ra2, rb2};
                if (tid < 16) sbuf[s1][256 + tid] = v4f{sa1, sb1, sa2, sb2};
            }
            if (p0 < NPAIR) __syncthreads();   // ONE barrier per 2 pairs

            // issue next interval's global loads (fly under 2x conv below)
            if (p0 + 2 < NPAIR) prefetchA(p0 + 2);
            if (p1i + 2 < NPAIR) prefetchB(p1i + 2);

            if (p0 < NPAIR)              hconv(s0, r0);
            if (p0 >= 5 && p0 < NPAIR)   vert(r0);
            if (p1i < NPAIR)             hconv(s1, r1);
            if (p1i >= 5 && p1i < NPAIR) vert(r1);
        }
    }

    float acc = accv.x + accv.y;
#pragma unroll
    for (int off = 32; off > 0; off >>= 1)
        acc += __shfl_down(acc, off, 64);
    if ((tid & 63) == 0) wsum[tid >> 6] = acc;
    __syncthreads();
    if (tid == 0) {
        double blocksum = 0.0;
#pragma unroll
        for (int w = 0; w < TPB / 64; ++w) blocksum += (double)wsum[w];
        atomicAdd(partial, blocksum);
    }
}

__global__ void ssim_finalize_kernel(const double* __restrict__ partial,
                                     float* __restrict__ out)
{
    out[0] = 1.0f - (float)(partial[0] / N_PIX);
}

extern "C" void kernel_launch(void* const* d_in, const int* in_sizes, int n_in,
                              void* d_out, int out_size, void* d_ws, size_t ws_size,
                              hipStream_t stream) {
    const float* img1 = (const float*)d_in[0];
    const float* img2 = (const float*)d_in[1];
    float* out = (float*)d_out;
    double* acc = (double*)d_ws;

    hipMemsetAsync(acc, 0, sizeof(double), stream);  // ws re-poisoned each launch

    dim3 grid(IMG / TPB, IMG / SH, PLANES);          // 2 x 8 x 96 = 1536 blocks
    ssim_map_kernel<<<grid, TPB, 0, stream>>>(img1, img2, acc);
    ssim_finalize_kernel<<<1, 1, 0, stream>>>(acc, out);
}